// Round 11
// baseline (148.854 us; speedup 1.0000x reference)
//
#include <hip/hip_runtime.h>

#define NN 4096
#define C 256
#define NH 4
#define CH 64
#define JSPLIT 8
#define JSLICE (NN / JSPLIT)     // 512
#define NJT (JSLICE / 32)        // 16

typedef float f32x4 __attribute__((ext_vector_type(4)));
typedef __bf16 b16x8 __attribute__((ext_vector_type(8)));
typedef unsigned short u16x8 __attribute__((ext_vector_type(8)));
typedef unsigned int u32x4 __attribute__((ext_vector_type(4)));
typedef _Float16 f16x2 __attribute__((ext_vector_type(2)));

__device__ inline float fast_exp2(float x) {
#if __has_builtin(__builtin_amdgcn_exp2f)
  return __builtin_amdgcn_exp2f(x);
#else
  return exp2f(x);
#endif
}

// pack two f32 -> (bf16(f0) | bf16(f1)<<16), round-half-up via +0x8000, v_perm pack
__device__ inline unsigned pack2bf(float f0, float f1) {
  unsigned u0 = __float_as_uint(f0) + 0x8000u;
  unsigned u1 = __float_as_uint(f1) + 0x8000u;
  return __builtin_amdgcn_perm(u1, u0, 0x07060302u);
}

// single-instruction f32 pair -> packed bf16 (lo = f0, hi = f1), RNE
__device__ inline unsigned cvtpk(float f0, float f1) {
  unsigned r;
  asm("v_cvt_pk_bf16_f32 %0, %1, %2" : "=v"(r) : "v"(f0), "v"(f1));
  return r;
}

// ---------------- Kernel 0: prep — X->bf16, W->bf16 transposed (small, ~2us)
__global__ __launch_bounds__(256) void k_prep(
    const float* __restrict__ X, const float* __restrict__ W,
    unsigned short* __restrict__ Xbf, unsigned short* __restrict__ WT) {
  const int b = blockIdx.x, t = threadIdx.x;
  if (b < 1024) {
    const int idx = b * 256 + t;
    const float4 v = ((const float4*)X)[idx];
    uint2 st;
    st.x = pack2bf(v.x, v.y);
    st.y = pack2bf(v.z, v.w);
    ((uint2*)Xbf)[idx] = st;
  } else {
    const int c = b - 1024;
    const float w = W[(size_t)t * C + c];
    WT[(size_t)c * C + t] = (unsigned short)((__float_as_uint(w) + 0x8000u) >> 16);
  }
}

// ---------------- Kernel 1: feats GEMM (blocks 0..255) MERGED with adj bit-packing
// (blocks 256..8447) so the 64MB adj stream overlaps the 255-idle-CU GEMM.
// Pack layout TRANSPOSED within each row's 64-byte slice-mask: byte (jt*4+q) is
// stored at (q*16+jt). k_attn's lane (q,n) then finds its 16 per-jt mask bytes
// CONTIGUOUS at offset q*16 — its dwordx4 preload needs no cross-lane bpermute
// (the LDS pipe was attn's serialization bottleneck; this removes its last user).
__global__ __launch_bounds__(256) void k_feats(
    const unsigned short* __restrict__ Xbf, const unsigned short* __restrict__ WT,
    const float* __restrict__ bias, const float* __restrict__ av,
    const int* __restrict__ adj, unsigned char* __restrict__ packed,
    unsigned short* __restrict__ F, float2* __restrict__ srcAB,
    float* __restrict__ Ed) {
  if (blockIdx.x >= 256) {
    const int idx = (blockIdx.x - 256) * 256 + threadIdx.x;
    const int4 a0 = *(const int4*)(adj + (size_t)idx * 8);
    const int4 a1 = *(const int4*)(adj + (size_t)idx * 8 + 4);
    unsigned m = 0;
    m |= (a0.x != 0) ? 1u : 0u;   m |= (a0.y != 0) ? 2u : 0u;
    m |= (a0.z != 0) ? 4u : 0u;   m |= (a0.w != 0) ? 8u : 0u;
    m |= (a1.x != 0) ? 16u : 0u;  m |= (a1.y != 0) ? 32u : 0u;
    m |= (a1.z != 0) ? 64u : 0u;  m |= (a1.w != 0) ? 128u : 0u;
    // transpose byte position within the 64-byte slice-mask block: c=jt*4+q -> q*16+jt
    const int newidx = (idx & ~63) | ((idx & 3) << 4) | ((idx >> 2) & 15);
    packed[newidx] = (unsigned char)m;
    return;
  }
  const int i0 = blockIdx.x * 16;
  const int h = threadIdx.x >> 6;
  const int lane = threadIdx.x & 63;
  const int q = lane >> 4, n = lane & 15;
  const int c0 = h * CH;
  const float LOG2E = 1.4426950408889634f;

  const f32x4 zero = {0.f, 0.f, 0.f, 0.f};
  f32x4 acc[4];
#pragma unroll
  for (int g = 0; g < 4; ++g) acc[g] = zero;

  const unsigned short* ap = Xbf + (size_t)(i0 + n) * C + q * 8;
#pragma unroll
  for (int kt = 0; kt < 8; ++kt) {
    const b16x8 aF = __builtin_bit_cast(b16x8, *(const u16x8*)(ap + kt * 32));
#pragma unroll
    for (int g = 0; g < 4; ++g) {
      const b16x8 bF = __builtin_bit_cast(b16x8,
          *(const u16x8*)(WT + (size_t)(c0 + g * 16 + n) * C + kt * 32 + q * 8));
      acc[g] = __builtin_amdgcn_mfma_f32_16x16x32_bf16(aF, bF, acc[g], 0, 0, 0);
    }
  }

  float fb[4][4], asv[4], adv[4];
#pragma unroll
  for (int g = 0; g < 4; ++g) {
    const float bs = bias[c0 + g * 16 + n];
    asv[g] = av[h * 128 + g * 16 + n];
    adv[g] = av[h * 128 + 64 + g * 16 + n];
#pragma unroll
    for (int r = 0; r < 4; ++r) fb[g][r] = acc[g][r] + bs;
  }
  const int jt = i0 >> 5, half = (i0 >> 4) & 1;
  const int qp = half * 2 + (q >> 1);
#pragma unroll
  for (int g = 0; g < 4; ++g) {
    uint2 st;
    st.x = pack2bf(fb[g][0], fb[g][1]);
    st.y = pack2bf(fb[g][2], fb[g][3]);
    *(uint2*)(F + ((size_t)((jt * NH + h) * 4 + g)) * 512 + (qp * 16 + n) * 8 + 4 * (q & 1)) = st;
  }
  // factored softmax: e_ij = max(e^{d_j}*A_i, e^{.2d_j}*B_i); A,B row-stable-scaled.
  // Ed is SoA: plane 0 = e^{d}, plane 1 = e^{.2d}
#pragma unroll
  for (int r = 0; r < 4; ++r) {
    float p = 0.f, d = 0.f;
#pragma unroll
    for (int g = 0; g < 4; ++g) {
      p = fmaf(fb[g][r], asv[g], p);
      d = fmaf(fb[g][r], adv[g], d);
    }
#pragma unroll
    for (int m = 1; m < 16; m <<= 1) {
      p += __shfl_xor(p, m);
      d += __shfl_xor(d, m);
    }
    if (n == 0) {
      const int row = i0 + q * 4 + r;
      const float dL = d * LOG2E;
      Ed[(size_t)h * NN + row] = fast_exp2(dL);
      Ed[(size_t)NH * NN + (size_t)h * NN + row] = fast_exp2(0.2f * dL);
      const float x = p + 16.0f;
      const float m2 = fmaxf(x, 0.2f * x) * LOG2E;
      srcAB[(size_t)row * NH + h] = make_float2(
          fast_exp2(fmaf(p, LOG2E, -m2)),
          fast_exp2(fmaf(0.2f * p, LOG2E, -m2)));
    }
  }
}

// ---------------- Kernel 2: masked-softmax attention + PV via MFMA
// wave = 16 rows x 1 head x 512 j; block = 16 rows x 4 heads; grid (8,256) =
// 2048 blocks = 8/CU. ZERO LDS ops and ZERO barriers in this kernel (r10 theory:
// the single per-CU LDS pipe serialized 5 DS ops/jt/wave ~= 13us across 32
// resident waves; r9's LDS staging was neutral-to-harmful for this reason):
//  - Ed planes read directly from global (L2-resident 128KB, 16-lane broadcast)
//  - masks: transposed pack layout makes per-jt extraction a register shift
// launch_bounds stays (256,4): min-waves 8 would cap 64 VGPR and spill (round 4).
__global__ __launch_bounds__(256, 4) void k_attn(
    const unsigned char* __restrict__ packed,
    const unsigned short* __restrict__ F,
    const float2* __restrict__ srcAB, const float* __restrict__ Ed,
    _Float16* __restrict__ pacc, float* __restrict__ lpart) {
  const int slice = blockIdx.x;
  const int i0 = blockIdx.y * 16;
  const int tid = threadIdx.x;
  const int h = tid >> 6;
  const int lane = tid & 63;
  const int q = lane >> 4, n = lane & 15;
  const int jbase = slice * JSLICE;

  const int r0 = i0 + n;
  const float2 ab0 = srcAB[(size_t)r0 * NH + h];

  const f32x4 zero = {0.f, 0.f, 0.f, 0.f};
  f32x4 acc[4], lacc = zero;
#pragma unroll
  for (int g = 0; g < 4; ++g) acc[g] = zero;

  u16x8 ou;
#pragma unroll
  for (int jj = 0; jj < 8; ++jj) ou[jj] = 0x3F80;
  const b16x8 ones = __builtin_bit_cast(b16x8, ou);

  // transposed-layout mask preload: lane (q,n)'s 16 per-jt bytes are contiguous
  const u32x4 m4 = *(const u32x4*)(packed + (size_t)r0 * 512 + (jbase >> 3) + q * 16);

  const float* pa = Ed + (size_t)h * NN + jbase;          // e^d plane
  const float* pb = pa + (size_t)NH * NN;                 // e^{.2d} plane
  const unsigned short* fp = F + ((size_t)((jbase >> 5) * NH + h) * 4) * 512 + lane * 8;

#pragma unroll
  for (int jt = 0; jt < NJT; ++jt) {
    // mask byte jt of this lane's transposed chunk: pure register math
    const unsigned Mb = (m4[jt >> 2] >> ((jt & 3) * 8)) & 0xffu;

    // SoA exp loads from global (16-lane broadcast within q-group, L2-hit)
    const int off = jt * 32 + q * 8;
    const f32x4 eA[2] = { *(const f32x4*)(pa + off), *(const f32x4*)(pa + off + 4) };
    const f32x4 eB[2] = { *(const f32x4*)(pb + off), *(const f32x4*)(pb + off + 4) };

    u32x4 pk;
#pragma unroll
    for (int hf = 0; hf < 2; ++hf) {
      const f32x4 xa = eA[hf] * ab0.x;   // v_pk_mul_f32 pairs
      const f32x4 xb = eB[hf] * ab0.y;
      float e[4];
#pragma unroll
      for (int t2 = 0; t2 < 4; ++t2) {
        const unsigned bit = 1u << (hf * 4 + t2);
        e[t2] = (Mb & bit) ? fmaxf(xa[t2], xb[t2]) : 0.f;
      }
      pk[hf * 2]     = cvtpk(e[0], e[1]);
      pk[hf * 2 + 1] = cvtpk(e[2], e[3]);
    }
    const b16x8 E = __builtin_bit_cast(b16x8, pk);
#pragma unroll
    for (int g = 0; g < 4; ++g) {
      const b16x8 bF = __builtin_bit_cast(b16x8,
          *(const u16x8*)(fp + (size_t)(jt * NH * 4 + g) * 512));
      acc[g] = __builtin_amdgcn_mfma_f32_16x16x32_bf16(E, bF, acc[g], 0, 0, 0);
    }
    lacc = __builtin_amdgcn_mfma_f32_16x16x32_bf16(E, ones, lacc, 0, 0, 0);
  }

#pragma unroll
  for (int g = 0; g < 4; ++g)
#pragma unroll
    for (int r = 0; r < 4; ++r) {
      const int col = h * CH + g * 16 + n;
      pacc[((size_t)slice * NN + i0 + q * 4 + r) * C + col] = (_Float16)acc[g][r];
    }
  if (n == 0) {
#pragma unroll
    for (int r = 0; r < 4; ++r)
      lpart[((size_t)slice * NN + i0 + q * 4 + r) * NH + h] = lacc[r];
  }
}

// ---------------- Kernel 3: combine j-slices, divide (vectorized: f16x2 loads)
__global__ __launch_bounds__(256) void k_final(
    const _Float16* __restrict__ pacc, const float* __restrict__ lpart,
    float* __restrict__ out) {
  const int t = threadIdx.x;
  const int row = blockIdx.x * 2 + (t >> 7);
  const int tc = t & 127;
  const int c2 = tc * 2;
  const int h = tc >> 5;
  float l = 0.f, sa0 = 0.f, sa1 = 0.f;
#pragma unroll
  for (int sp = 0; sp < JSPLIT; ++sp) {
    l += lpart[((size_t)sp * NN + row) * NH + h];
    const f16x2 v = *(const f16x2*)(pacc + ((size_t)sp * NN + row) * C + c2);
    sa0 += (float)v[0];
    sa1 += (float)v[1];
  }
  const float rl = 1.0f / l;
  *(float2*)(out + (size_t)row * C + c2) = make_float2(sa0 * rl, sa1 * rl);
}

extern "C" void kernel_launch(void* const* d_in, const int* in_sizes, int n_in,
                              void* d_out, int out_size, void* d_ws, size_t ws_size,
                              hipStream_t stream) {
  const float* nf   = (const float*)d_in[0];
  const int* adj    = (const int*)d_in[1];
  const float* W    = (const float*)d_in[2];
  const float* bias = (const float*)d_in[3];
  const float* av   = (const float*)d_in[4];
  float* out = (float*)d_out;

  char* ws = (char*)d_ws;
  unsigned char* packed  = (unsigned char*)ws;                              // 2 MB
  unsigned short* Xbf    = (unsigned short*)(ws + (2u << 20));              // 2 MB
  unsigned short* WT     = (unsigned short*)(ws + (4u << 20));              // 128 KB
  unsigned short* F      = (unsigned short*)(ws + (4u << 20) + (256u << 10)); // 2 MB
  float2* srcAB = (float2*)(ws + (6u << 20) + (256u << 10));                // 128 KB
  float* Ed     = (float*)(ws + (6u << 20) + (384u << 10));                 // 128 KB (2 planes)
  float* lpart  = (float*)(ws + (6u << 20) + (512u << 10));                 // 512 KB
  _Float16* pacc = (_Float16*)(ws + (8u << 20));                            // 16 MB

  k_prep<<<1280, 256, 0, stream>>>(nf, W, Xbf, WT);
  k_feats<<<8448, 256, 0, stream>>>(Xbf, WT, bias, av, adj, packed, F, srcAB, Ed);
  dim3 g2(JSPLIT, NN / 16);
  k_attn<<<g2, 256, 0, stream>>>(packed, F, srcAB, Ed, pacc, lpart);
  k_final<<<NN / 2, 256, 0, stream>>>(pacc, lpart, out);
}

// Round 12
// 137.137 us; speedup vs baseline: 1.0854x; 1.0854x over previous
//
#include <hip/hip_runtime.h>

#define NN 4096
#define C 256
#define NH 4
#define CH 64
#define JSPLIT 8
#define JSLICE (NN / JSPLIT)     // 512
#define NJT (JSLICE / 32)        // 16

typedef float f32x4 __attribute__((ext_vector_type(4)));
typedef __bf16 b16x8 __attribute__((ext_vector_type(8)));
typedef unsigned short u16x8 __attribute__((ext_vector_type(8)));
typedef unsigned int u32x4 __attribute__((ext_vector_type(4)));
typedef int i32x4 __attribute__((ext_vector_type(4)));
typedef _Float16 f16x2 __attribute__((ext_vector_type(2)));

#if __has_builtin(__builtin_amdgcn_raw_buffer_load_v4f32)
#define FBUF 1
#else
#define FBUF 0
#endif

__device__ inline float fast_exp2(float x) {
#if __has_builtin(__builtin_amdgcn_exp2f)
  return __builtin_amdgcn_exp2f(x);
#else
  return exp2f(x);
#endif
}

// pack two f32 -> (bf16(f0) | bf16(f1)<<16), round-half-up via +0x8000, v_perm pack
__device__ inline unsigned pack2bf(float f0, float f1) {
  unsigned u0 = __float_as_uint(f0) + 0x8000u;
  unsigned u1 = __float_as_uint(f1) + 0x8000u;
  return __builtin_amdgcn_perm(u1, u0, 0x07060302u);
}

// single-instruction f32 pair -> packed bf16 (lo = f0, hi = f1), RNE
__device__ inline unsigned cvtpk(float f0, float f1) {
  unsigned r;
  asm("v_cvt_pk_bf16_f32 %0, %1, %2" : "=v"(r) : "v"(f0), "v"(f1));
  return r;
}

// ---------------- Kernel 0: prep — X->bf16, W->bf16 transposed (small, ~2us)
__global__ __launch_bounds__(256) void k_prep(
    const float* __restrict__ X, const float* __restrict__ W,
    unsigned short* __restrict__ Xbf, unsigned short* __restrict__ WT) {
  const int b = blockIdx.x, t = threadIdx.x;
  if (b < 1024) {
    const int idx = b * 256 + t;
    const float4 v = ((const float4*)X)[idx];
    uint2 st;
    st.x = pack2bf(v.x, v.y);
    st.y = pack2bf(v.z, v.w);
    ((uint2*)Xbf)[idx] = st;
  } else {
    const int c = b - 1024;
    const float w = W[(size_t)t * C + c];
    WT[(size_t)c * C + t] = (unsigned short)((__float_as_uint(w) + 0x8000u) >> 16);
  }
}

// ---------------- Kernel 1: feats GEMM (blocks 0..255) MERGED with adj bit-packing
// (blocks 256..8447) so the 64MB adj stream overlaps the 255-idle-CU GEMM.
// Pack layout TRANSPOSED within each 64-byte slice-mask: byte (jt*4+q) stored at
// (q*16+jt) so k_attn lane (q,n)'s dwordx4 preload holds its 16 per-jt bytes
// contiguously — per-jt mask extraction is a register shift, no cross-lane op.
__global__ __launch_bounds__(256) void k_feats(
    const unsigned short* __restrict__ Xbf, const unsigned short* __restrict__ WT,
    const float* __restrict__ bias, const float* __restrict__ av,
    const int* __restrict__ adj, unsigned char* __restrict__ packed,
    unsigned short* __restrict__ F, float2* __restrict__ srcAB,
    float* __restrict__ Ed) {
  if (blockIdx.x >= 256) {
    const int idx = (blockIdx.x - 256) * 256 + threadIdx.x;
    const int4 a0 = *(const int4*)(adj + (size_t)idx * 8);
    const int4 a1 = *(const int4*)(adj + (size_t)idx * 8 + 4);
    unsigned m = 0;
    m |= (a0.x != 0) ? 1u : 0u;   m |= (a0.y != 0) ? 2u : 0u;
    m |= (a0.z != 0) ? 4u : 0u;   m |= (a0.w != 0) ? 8u : 0u;
    m |= (a1.x != 0) ? 16u : 0u;  m |= (a1.y != 0) ? 32u : 0u;
    m |= (a1.z != 0) ? 64u : 0u;  m |= (a1.w != 0) ? 128u : 0u;
    const int newidx = (idx & ~63) | ((idx & 3) << 4) | ((idx >> 2) & 15);
    packed[newidx] = (unsigned char)m;
    return;
  }
  const int i0 = blockIdx.x * 16;
  const int h = threadIdx.x >> 6;
  const int lane = threadIdx.x & 63;
  const int q = lane >> 4, n = lane & 15;
  const int c0 = h * CH;
  const float LOG2E = 1.4426950408889634f;

  const f32x4 zero = {0.f, 0.f, 0.f, 0.f};
  f32x4 acc[4];
#pragma unroll
  for (int g = 0; g < 4; ++g) acc[g] = zero;

  const unsigned short* ap = Xbf + (size_t)(i0 + n) * C + q * 8;
#pragma unroll
  for (int kt = 0; kt < 8; ++kt) {
    const b16x8 aF = __builtin_bit_cast(b16x8, *(const u16x8*)(ap + kt * 32));
#pragma unroll
    for (int g = 0; g < 4; ++g) {
      const b16x8 bF = __builtin_bit_cast(b16x8,
          *(const u16x8*)(WT + (size_t)(c0 + g * 16 + n) * C + kt * 32 + q * 8));
      acc[g] = __builtin_amdgcn_mfma_f32_16x16x32_bf16(aF, bF, acc[g], 0, 0, 0);
    }
  }

  float fb[4][4], asv[4], adv[4];
#pragma unroll
  for (int g = 0; g < 4; ++g) {
    const float bs = bias[c0 + g * 16 + n];
    asv[g] = av[h * 128 + g * 16 + n];
    adv[g] = av[h * 128 + 64 + g * 16 + n];
#pragma unroll
    for (int r = 0; r < 4; ++r) fb[g][r] = acc[g][r] + bs;
  }
  const int jt = i0 >> 5, half = (i0 >> 4) & 1;
  const int qp = half * 2 + (q >> 1);
#pragma unroll
  for (int g = 0; g < 4; ++g) {
    uint2 st;
    st.x = pack2bf(fb[g][0], fb[g][1]);
    st.y = pack2bf(fb[g][2], fb[g][3]);
    *(uint2*)(F + ((size_t)((jt * NH + h) * 4 + g)) * 512 + (qp * 16 + n) * 8 + 4 * (q & 1)) = st;
  }
  // factored softmax: e_ij = max(e^{d_j}*A_i, e^{.2d_j}*B_i); A,B row-stable-scaled.
  // Ed is SoA: plane 0 = e^{d}, plane 1 = e^{.2d}
#pragma unroll
  for (int r = 0; r < 4; ++r) {
    float p = 0.f, d = 0.f;
#pragma unroll
    for (int g = 0; g < 4; ++g) {
      p = fmaf(fb[g][r], asv[g], p);
      d = fmaf(fb[g][r], adv[g], d);
    }
#pragma unroll
    for (int m = 1; m < 16; m <<= 1) {
      p += __shfl_xor(p, m);
      d += __shfl_xor(d, m);
    }
    if (n == 0) {
      const int row = i0 + q * 4 + r;
      const float dL = d * LOG2E;
      Ed[(size_t)h * NN + row] = fast_exp2(dL);
      Ed[(size_t)NH * NN + (size_t)h * NN + row] = fast_exp2(0.2f * dL);
      const float x = p + 16.0f;
      const float m2 = fmaxf(x, 0.2f * x) * LOG2E;
      srcAB[(size_t)row * NH + h] = make_float2(
          fast_exp2(fmaf(p, LOG2E, -m2)),
          fast_exp2(fmaf(0.2f * p, LOG2E, -m2)));
    }
  }
}

// ---------------- Kernel 2: masked-softmax attention + PV via MFMA
// wave = 16 rows x 1 head x 512 j; grid (8, 256) = 2048 blocks = 8/CU.
// Issue-bound model (r9/r10/r11 retrodiction): attn time tracks per-jt instruction
// count. This round minimizes it:
//  - Ed in LDS (r10, restored): ds_read offsets are compile-time immediates,
//    ZERO addressing VALU/jt (r11's global Ed added 64-bit addr math -> +13%).
//  - transposed masks (r11, kept): per-jt extraction = 1 shift+and, no bpermute.
//  - F via SRSRC buffer_load: 32-bit voffset, g*1024 folds into offset: imm ->
//    1 v_add/jt replaces per-load 64-bit address materialization.
// launch_bounds stays (256,4): min-waves 8 would cap 64 VGPR and spill (round 4).
__global__ __launch_bounds__(256, 4) void k_attn(
    const unsigned char* __restrict__ packed,
    const unsigned short* __restrict__ F,
    const float2* __restrict__ srcAB, const float* __restrict__ Ed,
    _Float16* __restrict__ pacc, float* __restrict__ lpart) {
  __shared__ float sEd[NH * 2 * JSLICE];   // [h][plane][j] = 16 KB

  const int slice = blockIdx.x;
  const int i0 = blockIdx.y * 16;
  const int tid = threadIdx.x;
  const int h = tid >> 6;
  const int lane = tid & 63;
  const int q = lane >> 4, n = lane & 15;
  const int jbase = slice * JSLICE;

  // stage Ed for this slice (head h staged by its own 64 lanes; r10-proven)
#pragma unroll
  for (int v = 0; v < 4; ++v) {
    const int idx = v * 256 + lane * 4;          // 0..1023 within head
    const int pl = idx >> 9, j = idx & 511;
    const float4 vv = *(const float4*)(Ed + (size_t)pl * NH * NN
                                       + (size_t)h * NN + jbase + j);
    *(float4*)(&sEd[h * 1024 + idx]) = vv;
  }

  const int r0 = i0 + n;
  const float2 ab0 = srcAB[(size_t)r0 * NH + h];

  const f32x4 zero = {0.f, 0.f, 0.f, 0.f};
  f32x4 acc[4], lacc = zero;
#pragma unroll
  for (int g = 0; g < 4; ++g) acc[g] = zero;

  u16x8 ou;
#pragma unroll
  for (int jj = 0; jj < 8; ++jj) ou[jj] = 0x3F80;
  const b16x8 ones = __builtin_bit_cast(b16x8, ou);

  // transposed-layout mask preload: lane (q,n)'s 16 per-jt bytes are contiguous
  const u32x4 m4 = *(const u32x4*)(packed + (size_t)r0 * 512 + (jbase >> 3) + q * 16);

#if FBUF
  i32x4 frsrc;
  frsrc[0] = (int)(unsigned)(size_t)F;
  frsrc[1] = (int)(((size_t)F >> 32) & 0xFFFFu);  // stride 0, no swizzle
  frsrc[2] = (int)0xFFFFFFFFu;                    // bounds check disabled
  frsrc[3] = 0x00020000;                          // raw dword
  const unsigned fvoff =
      ((unsigned)((jbase >> 5) * 16 + h * 4)) * 1024u + (unsigned)lane * 16u;
#else
  const unsigned short* fp = F + ((size_t)((jbase >> 5) * NH + h) * 4) * 512 + lane * 8;
#endif
  const float* sB = &sEd[h * 1024];

  __syncthreads();   // sEd ready

#pragma unroll
  for (int jt = 0; jt < NJT; ++jt) {
    // mask byte jt of this lane's transposed chunk: pure register math
    const unsigned Mb = (m4[jt >> 2] >> ((jt & 3) * 8)) & 0xffu;

    // SoA exp loads from LDS (16-lane broadcast, compile-time offsets)
    const int off = jt * 32 + q * 8;
    const f32x4 eA[2] = { *(const f32x4*)(sB + off), *(const f32x4*)(sB + off + 4) };
    const f32x4 eB[2] = { *(const f32x4*)(sB + 512 + off),
                          *(const f32x4*)(sB + 512 + off + 4) };

    u32x4 pk;
#pragma unroll
    for (int hf = 0; hf < 2; ++hf) {
      const f32x4 xa = eA[hf] * ab0.x;   // v_pk_mul_f32 pairs
      const f32x4 xb = eB[hf] * ab0.y;
      float e[4];
#pragma unroll
      for (int t2 = 0; t2 < 4; ++t2) {
        const unsigned bit = 1u << (hf * 4 + t2);
        e[t2] = (Mb & bit) ? fmaxf(xa[t2], xb[t2]) : 0.f;
      }
      pk[hf * 2]     = cvtpk(e[0], e[1]);
      pk[hf * 2 + 1] = cvtpk(e[2], e[3]);
    }
    const b16x8 E = __builtin_bit_cast(b16x8, pk);
#pragma unroll
    for (int g = 0; g < 4; ++g) {
#if FBUF
      const f32x4 bv = __builtin_amdgcn_raw_buffer_load_v4f32(
          frsrc, fvoff + (unsigned)jt * 16384u + (unsigned)g * 1024u, 0, 0);
      const b16x8 bF = __builtin_bit_cast(b16x8, bv);
#else
      const b16x8 bF = __builtin_bit_cast(b16x8,
          *(const u16x8*)(fp + (size_t)(jt * NH * 4 + g) * 512));
#endif
      acc[g] = __builtin_amdgcn_mfma_f32_16x16x32_bf16(E, bF, acc[g], 0, 0, 0);
    }
    lacc = __builtin_amdgcn_mfma_f32_16x16x32_bf16(E, ones, lacc, 0, 0, 0);
  }

#pragma unroll
  for (int g = 0; g < 4; ++g)
#pragma unroll
    for (int r = 0; r < 4; ++r) {
      const int col = h * CH + g * 16 + n;
      pacc[((size_t)slice * NN + i0 + q * 4 + r) * C + col] = (_Float16)acc[g][r];
    }
  if (n == 0) {
#pragma unroll
    for (int r = 0; r < 4; ++r)
      lpart[((size_t)slice * NN + i0 + q * 4 + r) * NH + h] = lacc[r];
  }
}

// ---------------- Kernel 3: combine j-slices, divide (vectorized: f16x2 loads)
__global__ __launch_bounds__(256) void k_final(
    const _Float16* __restrict__ pacc, const float* __restrict__ lpart,
    float* __restrict__ out) {
  const int t = threadIdx.x;
  const int row = blockIdx.x * 2 + (t >> 7);
  const int tc = t & 127;
  const int c2 = tc * 2;
  const int h = tc >> 5;
  float l = 0.f, sa0 = 0.f, sa1 = 0.f;
#pragma unroll
  for (int sp = 0; sp < JSPLIT; ++sp) {
    l += lpart[((size_t)sp * NN + row) * NH + h];
    const f16x2 v = *(const f16x2*)(pacc + ((size_t)sp * NN + row) * C + c2);
    sa0 += (float)v[0];
    sa1 += (float)v[1];
  }
  const float rl = 1.0f / l;
  *(float2*)(out + (size_t)row * C + c2) = make_float2(sa0 * rl, sa1 * rl);
}

extern "C" void kernel_launch(void* const* d_in, const int* in_sizes, int n_in,
                              void* d_out, int out_size, void* d_ws, size_t ws_size,
                              hipStream_t stream) {
  const float* nf   = (const float*)d_in[0];
  const int* adj    = (const int*)d_in[1];
  const float* W    = (const float*)d_in[2];
  const float* bias = (const float*)d_in[3];
  const float* av   = (const float*)d_in[4];
  float* out = (float*)d_out;

  char* ws = (char*)d_ws;
  unsigned char* packed  = (unsigned char*)ws;                              // 2 MB
  unsigned short* Xbf    = (unsigned short*)(ws + (2u << 20));              // 2 MB
  unsigned short* WT     = (unsigned short*)(ws + (4u << 20));              // 128 KB
  unsigned short* F      = (unsigned short*)(ws + (4u << 20) + (256u << 10)); // 2 MB
  float2* srcAB = (float2*)(ws + (6u << 20) + (256u << 10));                // 128 KB
  float* Ed     = (float*)(ws + (6u << 20) + (384u << 10));                 // 128 KB (2 planes)
  float* lpart  = (float*)(ws + (6u << 20) + (512u << 10));                 // 512 KB
  _Float16* pacc = (_Float16*)(ws + (8u << 20));                            // 16 MB

  k_prep<<<1280, 256, 0, stream>>>(nf, W, Xbf, WT);
  k_feats<<<8448, 256, 0, stream>>>(Xbf, WT, bias, av, adj, packed, F, srcAB, Ed);
  dim3 g2(JSPLIT, NN / 16);
  k_attn<<<g2, 256, 0, stream>>>(packed, F, srcAB, Ed, pacc, lpart);
  k_final<<<NN / 2, 256, 0, stream>>>(pacc, lpart, out);
}

// Round 13
// 135.376 us; speedup vs baseline: 1.0996x; 1.0130x over previous
//
#include <hip/hip_runtime.h>

#define NN 4096
#define C 256
#define NH 4
#define CH 64
#define JSPLIT 8
#define JSLICE (NN / JSPLIT)     // 512
#define NJT (JSLICE / 32)        // 16

typedef float f32x4 __attribute__((ext_vector_type(4)));
typedef __bf16 b16x8 __attribute__((ext_vector_type(8)));
typedef unsigned short u16x8 __attribute__((ext_vector_type(8)));
typedef unsigned int u32x4 __attribute__((ext_vector_type(4)));
typedef int i32x4 __attribute__((ext_vector_type(4)));
typedef _Float16 f16x2 __attribute__((ext_vector_type(2)));

#if __has_builtin(__builtin_amdgcn_raw_buffer_load_v4f32)
#define FBUF 1
#else
#define FBUF 0
#endif

__device__ inline float fast_exp2(float x) {
#if __has_builtin(__builtin_amdgcn_exp2f)
  return __builtin_amdgcn_exp2f(x);
#else
  return exp2f(x);
#endif
}

// pack two f32 -> (bf16(f0) | bf16(f1)<<16), round-half-up via +0x8000, v_perm pack
__device__ inline unsigned pack2bf(float f0, float f1) {
  unsigned u0 = __float_as_uint(f0) + 0x8000u;
  unsigned u1 = __float_as_uint(f1) + 0x8000u;
  return __builtin_amdgcn_perm(u1, u0, 0x07060302u);
}

// single-instruction f32 pair -> packed bf16 (lo = f0, hi = f1), RNE
__device__ inline unsigned cvtpk(float f0, float f1) {
  unsigned r;
  asm("v_cvt_pk_bf16_f32 %0, %1, %2" : "=v"(r) : "v"(f0), "v"(f1));
  return r;
}

// ---------------- Kernel 0: prep — X->bf16, W->bf16 transposed (small, ~2us)
__global__ __launch_bounds__(256) void k_prep(
    const float* __restrict__ X, const float* __restrict__ W,
    unsigned short* __restrict__ Xbf, unsigned short* __restrict__ WT) {
  const int b = blockIdx.x, t = threadIdx.x;
  if (b < 1024) {
    const int idx = b * 256 + t;
    const float4 v = ((const float4*)X)[idx];
    uint2 st;
    st.x = pack2bf(v.x, v.y);
    st.y = pack2bf(v.z, v.w);
    ((uint2*)Xbf)[idx] = st;
  } else {
    const int c = b - 1024;
    const float w = W[(size_t)t * C + c];
    WT[(size_t)c * C + t] = (unsigned short)((__float_as_uint(w) + 0x8000u) >> 16);
  }
}

// ---------------- Kernel 1: feats GEMM (blocks 0..255) MERGED with adj bit-packing
// (blocks 256..8447) so the 64MB adj stream overlaps the 255-idle-CU GEMM.
// Pack layout TRANSPOSED within each 64-byte slice-mask: byte (jt*4+q) stored at
// (q*16+jt) so k_attn lane (q,n)'s dwordx4 preload holds its 16 per-jt bytes
// contiguously — per-jt mask extraction is a register shift, no cross-lane op.
__global__ __launch_bounds__(256) void k_feats(
    const unsigned short* __restrict__ Xbf, const unsigned short* __restrict__ WT,
    const float* __restrict__ bias, const float* __restrict__ av,
    const int* __restrict__ adj, unsigned char* __restrict__ packed,
    unsigned short* __restrict__ F, float2* __restrict__ srcAB,
    float* __restrict__ Ed) {
  if (blockIdx.x >= 256) {
    const int idx = (blockIdx.x - 256) * 256 + threadIdx.x;
    const int4 a0 = *(const int4*)(adj + (size_t)idx * 8);
    const int4 a1 = *(const int4*)(adj + (size_t)idx * 8 + 4);
    unsigned m = 0;
    m |= (a0.x != 0) ? 1u : 0u;   m |= (a0.y != 0) ? 2u : 0u;
    m |= (a0.z != 0) ? 4u : 0u;   m |= (a0.w != 0) ? 8u : 0u;
    m |= (a1.x != 0) ? 16u : 0u;  m |= (a1.y != 0) ? 32u : 0u;
    m |= (a1.z != 0) ? 64u : 0u;  m |= (a1.w != 0) ? 128u : 0u;
    const int newidx = (idx & ~63) | ((idx & 3) << 4) | ((idx >> 2) & 15);
    packed[newidx] = (unsigned char)m;
    return;
  }
  const int i0 = blockIdx.x * 16;
  const int h = threadIdx.x >> 6;
  const int lane = threadIdx.x & 63;
  const int q = lane >> 4, n = lane & 15;
  const int c0 = h * CH;
  const float LOG2E = 1.4426950408889634f;

  const f32x4 zero = {0.f, 0.f, 0.f, 0.f};
  f32x4 acc[4];
#pragma unroll
  for (int g = 0; g < 4; ++g) acc[g] = zero;

  const unsigned short* ap = Xbf + (size_t)(i0 + n) * C + q * 8;
#pragma unroll
  for (int kt = 0; kt < 8; ++kt) {
    const b16x8 aF = __builtin_bit_cast(b16x8, *(const u16x8*)(ap + kt * 32));
#pragma unroll
    for (int g = 0; g < 4; ++g) {
      const b16x8 bF = __builtin_bit_cast(b16x8,
          *(const u16x8*)(WT + (size_t)(c0 + g * 16 + n) * C + kt * 32 + q * 8));
      acc[g] = __builtin_amdgcn_mfma_f32_16x16x32_bf16(aF, bF, acc[g], 0, 0, 0);
    }
  }

  float fb[4][4], asv[4], adv[4];
#pragma unroll
  for (int g = 0; g < 4; ++g) {
    const float bs = bias[c0 + g * 16 + n];
    asv[g] = av[h * 128 + g * 16 + n];
    adv[g] = av[h * 128 + 64 + g * 16 + n];
#pragma unroll
    for (int r = 0; r < 4; ++r) fb[g][r] = acc[g][r] + bs;
  }
  const int jt = i0 >> 5, half = (i0 >> 4) & 1;
  const int qp = half * 2 + (q >> 1);
#pragma unroll
  for (int g = 0; g < 4; ++g) {
    uint2 st;
    st.x = pack2bf(fb[g][0], fb[g][1]);
    st.y = pack2bf(fb[g][2], fb[g][3]);
    *(uint2*)(F + ((size_t)((jt * NH + h) * 4 + g)) * 512 + (qp * 16 + n) * 8 + 4 * (q & 1)) = st;
  }
  // factored softmax: e_ij = max(e^{d_j}*A_i, e^{.2d_j}*B_i); A,B row-stable-scaled.
  // Ed is SoA: plane 0 = e^{d}, plane 1 = e^{.2d}
#pragma unroll
  for (int r = 0; r < 4; ++r) {
    float p = 0.f, d = 0.f;
#pragma unroll
    for (int g = 0; g < 4; ++g) {
      p = fmaf(fb[g][r], asv[g], p);
      d = fmaf(fb[g][r], adv[g], d);
    }
#pragma unroll
    for (int m = 1; m < 16; m <<= 1) {
      p += __shfl_xor(p, m);
      d += __shfl_xor(d, m);
    }
    if (n == 0) {
      const int row = i0 + q * 4 + r;
      const float dL = d * LOG2E;
      Ed[(size_t)h * NN + row] = fast_exp2(dL);
      Ed[(size_t)NH * NN + (size_t)h * NN + row] = fast_exp2(0.2f * dL);
      const float x = p + 16.0f;
      const float m2 = fmaxf(x, 0.2f * x) * LOG2E;
      srcAB[(size_t)row * NH + h] = make_float2(
          fast_exp2(fmaf(p, LOG2E, -m2)),
          fast_exp2(fmaf(0.2f * p, LOG2E, -m2)));
    }
  }
}

// ---------------- Kernel 2: masked-softmax attention + PV via MFMA
// r13: wave = 32 rows x 1 head (TWO accumulator sets) x 512 j. The same 4 F
// buffer-loads + 4 Ed ds_reads per jt now serve BOTH row-groups, halving the two
// dominant per-CU pipe terms (F L1-return ~13us -> ~6.6, LDS ~10 -> ~5) that
// r12's 16-row waves paid per 16 rows. Grid (8,128) = 1024 blocks = 16 waves/CU;
// r12's lean loop has ~2x the per-wave ILP of r1's fat loop that failed at this
// occupancy. All r12 opts kept: Ed-LDS (imm-offset ds_read), transposed masks
// (register shift, no bpermute), SRSRC F loads (32-bit voffset, imm-folded).
// launch_bounds stays (256,4): min-waves 8 would cap 64 VGPR and spill (round 4).
__global__ __launch_bounds__(256, 4) void k_attn(
    const unsigned char* __restrict__ packed,
    const unsigned short* __restrict__ F,
    const float2* __restrict__ srcAB, const float* __restrict__ Ed,
    _Float16* __restrict__ pacc, float* __restrict__ lpart) {
  __shared__ float sEd[NH * 2 * JSLICE];   // [h][plane][j] = 16 KB

  const int slice = blockIdx.x;
  const int i0 = blockIdx.y * 32;
  const int tid = threadIdx.x;
  const int h = tid >> 6;
  const int lane = tid & 63;
  const int q = lane >> 4, n = lane & 15;
  const int jbase = slice * JSLICE;

  // stage Ed for this slice (head h staged by its own 64 lanes; r10-proven)
#pragma unroll
  for (int v = 0; v < 4; ++v) {
    const int idx = v * 256 + lane * 4;          // 0..1023 within head
    const int pl = idx >> 9, j = idx & 511;
    const float4 vv = *(const float4*)(Ed + (size_t)pl * NH * NN
                                       + (size_t)h * NN + jbase + j);
    *(float4*)(&sEd[h * 1024 + idx]) = vv;
  }

  const int r0 = i0 + n, r1 = i0 + 16 + n;
  const float2 ab0 = srcAB[(size_t)r0 * NH + h];
  const float2 ab1 = srcAB[(size_t)r1 * NH + h];

  const f32x4 zero = {0.f, 0.f, 0.f, 0.f};
  f32x4 acc0[4], acc1[4], lacc0 = zero, lacc1 = zero;
#pragma unroll
  for (int g = 0; g < 4; ++g) { acc0[g] = zero; acc1[g] = zero; }

  u16x8 ou;
#pragma unroll
  for (int jj = 0; jj < 8; ++jj) ou[jj] = 0x3F80;
  const b16x8 ones = __builtin_bit_cast(b16x8, ou);

  // transposed-layout mask preloads: lane (q,n)'s 16 per-jt bytes contiguous
  const u32x4 m40 = *(const u32x4*)(packed + (size_t)r0 * 512 + (jbase >> 3) + q * 16);
  const u32x4 m41 = *(const u32x4*)(packed + (size_t)r1 * 512 + (jbase >> 3) + q * 16);

#if FBUF
  i32x4 frsrc;
  frsrc[0] = (int)(unsigned)(size_t)F;
  frsrc[1] = (int)(((size_t)F >> 32) & 0xFFFFu);  // stride 0, no swizzle
  frsrc[2] = (int)0xFFFFFFFFu;                    // bounds check disabled
  frsrc[3] = 0x00020000;                          // raw dword
  const unsigned fvoff =
      ((unsigned)((jbase >> 5) * 16 + h * 4)) * 1024u + (unsigned)lane * 16u;
#else
  const unsigned short* fp = F + ((size_t)((jbase >> 5) * NH + h) * 4) * 512 + lane * 8;
#endif
  const float* sB = &sEd[h * 1024];

  __syncthreads();   // sEd ready

#pragma unroll
  for (int jt = 0; jt < NJT; ++jt) {
    // mask byte jt of each row's transposed chunk: pure register math
    const unsigned Mb0 = (m40[jt >> 2] >> ((jt & 3) * 8)) & 0xffu;
    const unsigned Mb1 = (m41[jt >> 2] >> ((jt & 3) * 8)) & 0xffu;

    // SoA exp loads from LDS (shared by both row-groups, compile-time offsets)
    const int off = jt * 32 + q * 8;
    const f32x4 eA[2] = { *(const f32x4*)(sB + off), *(const f32x4*)(sB + off + 4) };
    const f32x4 eB[2] = { *(const f32x4*)(sB + 512 + off),
                          *(const f32x4*)(sB + 512 + off + 4) };

    u32x4 pk0, pk1;
#pragma unroll
    for (int hf = 0; hf < 2; ++hf) {
      const f32x4 xa0 = eA[hf] * ab0.x;   // v_pk_mul_f32 pairs
      const f32x4 xb0 = eB[hf] * ab0.y;
      const f32x4 xa1 = eA[hf] * ab1.x;
      const f32x4 xb1 = eB[hf] * ab1.y;
      float e0[4], e1[4];
#pragma unroll
      for (int t2 = 0; t2 < 4; ++t2) {
        const unsigned bit = 1u << (hf * 4 + t2);
        e0[t2] = (Mb0 & bit) ? fmaxf(xa0[t2], xb0[t2]) : 0.f;
        e1[t2] = (Mb1 & bit) ? fmaxf(xa1[t2], xb1[t2]) : 0.f;
      }
      pk0[hf * 2]     = cvtpk(e0[0], e0[1]);
      pk0[hf * 2 + 1] = cvtpk(e0[2], e0[3]);
      pk1[hf * 2]     = cvtpk(e1[0], e1[1]);
      pk1[hf * 2 + 1] = cvtpk(e1[2], e1[3]);
    }
    const b16x8 E0 = __builtin_bit_cast(b16x8, pk0);
    const b16x8 E1 = __builtin_bit_cast(b16x8, pk1);
#pragma unroll
    for (int g = 0; g < 4; ++g) {
#if FBUF
      const f32x4 bv = __builtin_amdgcn_raw_buffer_load_v4f32(
          frsrc, fvoff + (unsigned)jt * 16384u + (unsigned)g * 1024u, 0, 0);
      const b16x8 bF = __builtin_bit_cast(b16x8, bv);
#else
      const b16x8 bF = __builtin_bit_cast(b16x8,
          *(const u16x8*)(fp + (size_t)(jt * NH * 4 + g) * 512));
#endif
      acc0[g] = __builtin_amdgcn_mfma_f32_16x16x32_bf16(E0, bF, acc0[g], 0, 0, 0);
      acc1[g] = __builtin_amdgcn_mfma_f32_16x16x32_bf16(E1, bF, acc1[g], 0, 0, 0);
    }
    lacc0 = __builtin_amdgcn_mfma_f32_16x16x32_bf16(E0, ones, lacc0, 0, 0, 0);
    lacc1 = __builtin_amdgcn_mfma_f32_16x16x32_bf16(E1, ones, lacc1, 0, 0, 0);
  }

#pragma unroll
  for (int g = 0; g < 4; ++g)
#pragma unroll
    for (int r = 0; r < 4; ++r) {
      const int col = h * CH + g * 16 + n;
      pacc[((size_t)slice * NN + i0 + q * 4 + r) * C + col] = (_Float16)acc0[g][r];
      pacc[((size_t)slice * NN + i0 + 16 + q * 4 + r) * C + col] = (_Float16)acc1[g][r];
    }
  if (n == 0) {
#pragma unroll
    for (int r = 0; r < 4; ++r) {
      lpart[((size_t)slice * NN + i0 + q * 4 + r) * NH + h] = lacc0[r];
      lpart[((size_t)slice * NN + i0 + 16 + q * 4 + r) * NH + h] = lacc1[r];
    }
  }
}

// ---------------- Kernel 3: combine j-slices, divide (vectorized: f16x2 loads)
__global__ __launch_bounds__(256) void k_final(
    const _Float16* __restrict__ pacc, const float* __restrict__ lpart,
    float* __restrict__ out) {
  const int t = threadIdx.x;
  const int row = blockIdx.x * 2 + (t >> 7);
  const int tc = t & 127;
  const int c2 = tc * 2;
  const int h = tc >> 5;
  float l = 0.f, sa0 = 0.f, sa1 = 0.f;
#pragma unroll
  for (int sp = 0; sp < JSPLIT; ++sp) {
    l += lpart[((size_t)sp * NN + row) * NH + h];
    const f16x2 v = *(const f16x2*)(pacc + ((size_t)sp * NN + row) * C + c2);
    sa0 += (float)v[0];
    sa1 += (float)v[1];
  }
  const float rl = 1.0f / l;
  *(float2*)(out + (size_t)row * C + c2) = make_float2(sa0 * rl, sa1 * rl);
}

extern "C" void kernel_launch(void* const* d_in, const int* in_sizes, int n_in,
                              void* d_out, int out_size, void* d_ws, size_t ws_size,
                              hipStream_t stream) {
  const float* nf   = (const float*)d_in[0];
  const int* adj    = (const int*)d_in[1];
  const float* W    = (const float*)d_in[2];
  const float* bias = (const float*)d_in[3];
  const float* av   = (const float*)d_in[4];
  float* out = (float*)d_out;

  char* ws = (char*)d_ws;
  unsigned char* packed  = (unsigned char*)ws;                              // 2 MB
  unsigned short* Xbf    = (unsigned short*)(ws + (2u << 20));              // 2 MB
  unsigned short* WT     = (unsigned short*)(ws + (4u << 20));              // 128 KB
  unsigned short* F      = (unsigned short*)(ws + (4u << 20) + (256u << 10)); // 2 MB
  float2* srcAB = (float2*)(ws + (6u << 20) + (256u << 10));                // 128 KB
  float* Ed     = (float*)(ws + (6u << 20) + (384u << 10));                 // 128 KB (2 planes)
  float* lpart  = (float*)(ws + (6u << 20) + (512u << 10));                 // 512 KB
  _Float16* pacc = (_Float16*)(ws + (8u << 20));                            // 16 MB

  k_prep<<<1280, 256, 0, stream>>>(nf, W, Xbf, WT);
  k_feats<<<8448, 256, 0, stream>>>(Xbf, WT, bias, av, adj, packed, F, srcAB, Ed);
  dim3 g2(JSPLIT, NN / 32);
  k_attn<<<g2, 256, 0, stream>>>(packed, F, srcAB, Ed, pacc, lpart);
  k_final<<<NN / 2, 256, 0, stream>>>(pacc, lpart, out);
}

// Round 14
// 134.997 us; speedup vs baseline: 1.1026x; 1.0028x over previous
//
#include <hip/hip_runtime.h>

#define NN 4096
#define C 256
#define NH 4
#define CH 64
#define JSPLIT 8
#define JSLICE (NN / JSPLIT)     // 512
#define NJT (JSLICE / 32)        // 16

typedef float f32x4 __attribute__((ext_vector_type(4)));
typedef __bf16 b16x8 __attribute__((ext_vector_type(8)));
typedef unsigned short u16x8 __attribute__((ext_vector_type(8)));
typedef unsigned int u32x4 __attribute__((ext_vector_type(4)));
typedef int i32x4 __attribute__((ext_vector_type(4)));
typedef _Float16 f16x2 __attribute__((ext_vector_type(2)));

#if __has_builtin(__builtin_amdgcn_raw_buffer_load_v4f32)
#define FBUF 1
#else
#define FBUF 0
#endif

__device__ inline float fast_exp2(float x) {
#if __has_builtin(__builtin_amdgcn_exp2f)
  return __builtin_amdgcn_exp2f(x);
#else
  return exp2f(x);
#endif
}

// pack two f32 -> (bf16(f0) | bf16(f1)<<16), round-half-up via +0x8000, v_perm pack
__device__ inline unsigned pack2bf(float f0, float f1) {
  unsigned u0 = __float_as_uint(f0) + 0x8000u;
  unsigned u1 = __float_as_uint(f1) + 0x8000u;
  return __builtin_amdgcn_perm(u1, u0, 0x07060302u);
}

// single-instruction f32 pair -> packed bf16 (lo = f0, hi = f1), RNE
__device__ inline unsigned cvtpk(float f0, float f1) {
  unsigned r;
  asm("v_cvt_pk_bf16_f32 %0, %1, %2" : "=v"(r) : "v"(f0), "v"(f1));
  return r;
}

// ---------------- Kernel 0: prep — X->bf16, W->bf16 transposed (small, ~2us)
__global__ __launch_bounds__(256) void k_prep(
    const float* __restrict__ X, const float* __restrict__ W,
    unsigned short* __restrict__ Xbf, unsigned short* __restrict__ WT) {
  const int b = blockIdx.x, t = threadIdx.x;
  if (b < 1024) {
    const int idx = b * 256 + t;
    const float4 v = ((const float4*)X)[idx];
    uint2 st;
    st.x = pack2bf(v.x, v.y);
    st.y = pack2bf(v.z, v.w);
    ((uint2*)Xbf)[idx] = st;
  } else {
    const int c = b - 1024;
    const float w = W[(size_t)t * C + c];
    WT[(size_t)c * C + t] = (unsigned short)((__float_as_uint(w) + 0x8000u) >> 16);
  }
}

// ---------------- Kernel 1: feats GEMM (blocks 0..255) MERGED with adj bit-packing
// (blocks 256..8447) so the 64MB adj stream overlaps the 255-idle-CU GEMM.
// Pack layout TRANSPOSED within each 64-byte slice-mask: byte (jt*4+q) stored at
// (q*16+jt) so k_attn lane (q,n)'s dwordx4 preload holds its 16 per-jt bytes
// contiguously — per-jt mask extraction is a register shift, no cross-lane op.
__global__ __launch_bounds__(256) void k_feats(
    const unsigned short* __restrict__ Xbf, const unsigned short* __restrict__ WT,
    const float* __restrict__ bias, const float* __restrict__ av,
    const int* __restrict__ adj, unsigned char* __restrict__ packed,
    unsigned short* __restrict__ F, float2* __restrict__ srcAB,
    float* __restrict__ Ed) {
  if (blockIdx.x >= 256) {
    const int idx = (blockIdx.x - 256) * 256 + threadIdx.x;
    const int4 a0 = *(const int4*)(adj + (size_t)idx * 8);
    const int4 a1 = *(const int4*)(adj + (size_t)idx * 8 + 4);
    unsigned m = 0;
    m |= (a0.x != 0) ? 1u : 0u;   m |= (a0.y != 0) ? 2u : 0u;
    m |= (a0.z != 0) ? 4u : 0u;   m |= (a0.w != 0) ? 8u : 0u;
    m |= (a1.x != 0) ? 16u : 0u;  m |= (a1.y != 0) ? 32u : 0u;
    m |= (a1.z != 0) ? 64u : 0u;  m |= (a1.w != 0) ? 128u : 0u;
    const int newidx = (idx & ~63) | ((idx & 3) << 4) | ((idx >> 2) & 15);
    packed[newidx] = (unsigned char)m;
    return;
  }
  const int i0 = blockIdx.x * 16;
  const int h = threadIdx.x >> 6;
  const int lane = threadIdx.x & 63;
  const int q = lane >> 4, n = lane & 15;
  const int c0 = h * CH;
  const float LOG2E = 1.4426950408889634f;

  const f32x4 zero = {0.f, 0.f, 0.f, 0.f};
  f32x4 acc[4];
#pragma unroll
  for (int g = 0; g < 4; ++g) acc[g] = zero;

  const unsigned short* ap = Xbf + (size_t)(i0 + n) * C + q * 8;
#pragma unroll
  for (int kt = 0; kt < 8; ++kt) {
    const b16x8 aF = __builtin_bit_cast(b16x8, *(const u16x8*)(ap + kt * 32));
#pragma unroll
    for (int g = 0; g < 4; ++g) {
      const b16x8 bF = __builtin_bit_cast(b16x8,
          *(const u16x8*)(WT + (size_t)(c0 + g * 16 + n) * C + kt * 32 + q * 8));
      acc[g] = __builtin_amdgcn_mfma_f32_16x16x32_bf16(aF, bF, acc[g], 0, 0, 0);
    }
  }

  float fb[4][4], asv[4], adv[4];
#pragma unroll
  for (int g = 0; g < 4; ++g) {
    const float bs = bias[c0 + g * 16 + n];
    asv[g] = av[h * 128 + g * 16 + n];
    adv[g] = av[h * 128 + 64 + g * 16 + n];
#pragma unroll
    for (int r = 0; r < 4; ++r) fb[g][r] = acc[g][r] + bs;
  }
  const int jt = i0 >> 5, half = (i0 >> 4) & 1;
  const int qp = half * 2 + (q >> 1);
#pragma unroll
  for (int g = 0; g < 4; ++g) {
    uint2 st;
    st.x = pack2bf(fb[g][0], fb[g][1]);
    st.y = pack2bf(fb[g][2], fb[g][3]);
    *(uint2*)(F + ((size_t)((jt * NH + h) * 4 + g)) * 512 + (qp * 16 + n) * 8 + 4 * (q & 1)) = st;
  }
  // factored softmax: e_ij = max(e^{d_j}*A_i, e^{.2d_j}*B_i); A,B row-stable-scaled.
  // Ed is SoA: plane 0 = e^{d}, plane 1 = e^{.2d}
#pragma unroll
  for (int r = 0; r < 4; ++r) {
    float p = 0.f, d = 0.f;
#pragma unroll
    for (int g = 0; g < 4; ++g) {
      p = fmaf(fb[g][r], asv[g], p);
      d = fmaf(fb[g][r], adv[g], d);
    }
#pragma unroll
    for (int m = 1; m < 16; m <<= 1) {
      p += __shfl_xor(p, m);
      d += __shfl_xor(d, m);
    }
    if (n == 0) {
      const int row = i0 + q * 4 + r;
      const float dL = d * LOG2E;
      Ed[(size_t)h * NN + row] = fast_exp2(dL);
      Ed[(size_t)NH * NN + (size_t)h * NN + row] = fast_exp2(0.2f * dL);
      const float x = p + 16.0f;
      const float m2 = fmaxf(x, 0.2f * x) * LOG2E;
      srcAB[(size_t)row * NH + h] = make_float2(
          fast_exp2(fmaf(p, LOG2E, -m2)),
          fast_exp2(fmaf(0.2f * p, LOG2E, -m2)));
    }
  }
}

// ---------------- Kernel 2: masked-softmax attention + PV via MFMA
// r14: wave = 64 rows x 1 head (FOUR accumulator groups) x 512 j. The same 4 F
// buffer-loads + 4 Ed ds_reads per jt serve all 4 row-groups: total F/ds
// instruction count drops another 2x vs r13 (the quantity attn time has tracked
// across r12->r13). Grid (8,64) = 512 blocks = 2/CU = 8 waves/CU; TLP is low but
// each wave carries 4 independent E-chains of ILP and the loop is barrier-free.
// launch_bounds (256,2): RELAXES the VGPR cap to 256 for ~190 live regs
// (4x20 acc + 4 masks + 4 ab + fragments). (256,4) would cap 128 -> spill; the
// round-4 disaster was declaring 8 (cap 64). Check: localMem must stay 0.
__global__ __launch_bounds__(256, 2) void k_attn(
    const unsigned char* __restrict__ packed,
    const unsigned short* __restrict__ F,
    const float2* __restrict__ srcAB, const float* __restrict__ Ed,
    _Float16* __restrict__ pacc, float* __restrict__ lpart) {
  __shared__ float sEd[NH * 2 * JSLICE];   // [h][plane][j] = 16 KB

  const int slice = blockIdx.x;
  const int i0 = blockIdx.y * 64;
  const int tid = threadIdx.x;
  const int h = tid >> 6;
  const int lane = tid & 63;
  const int q = lane >> 4, n = lane & 15;
  const int jbase = slice * JSLICE;

  // stage Ed for this slice (head h staged by its own 64 lanes; r10-proven)
#pragma unroll
  for (int v = 0; v < 4; ++v) {
    const int idx = v * 256 + lane * 4;          // 0..1023 within head
    const int pl = idx >> 9, j = idx & 511;
    const float4 vv = *(const float4*)(Ed + (size_t)pl * NH * NN
                                       + (size_t)h * NN + jbase + j);
    *(float4*)(&sEd[h * 1024 + idx]) = vv;
  }

  const f32x4 zero = {0.f, 0.f, 0.f, 0.f};
  float2 ab[4];
  u32x4 m4[4];
  f32x4 acc[4][4], lacc[4];
#pragma unroll
  for (int rg = 0; rg < 4; ++rg) {
    const int rr = i0 + rg * 16 + n;
    ab[rg] = srcAB[(size_t)rr * NH + h];
    m4[rg] = *(const u32x4*)(packed + (size_t)rr * 512 + (jbase >> 3) + q * 16);
    lacc[rg] = zero;
#pragma unroll
    for (int g = 0; g < 4; ++g) acc[rg][g] = zero;
  }

  u16x8 ou;
#pragma unroll
  for (int jj = 0; jj < 8; ++jj) ou[jj] = 0x3F80;
  const b16x8 ones = __builtin_bit_cast(b16x8, ou);

#if FBUF
  i32x4 frsrc;
  frsrc[0] = (int)(unsigned)(size_t)F;
  frsrc[1] = (int)(((size_t)F >> 32) & 0xFFFFu);  // stride 0, no swizzle
  frsrc[2] = (int)0xFFFFFFFFu;                    // bounds check disabled
  frsrc[3] = 0x00020000;                          // raw dword
  const unsigned fvoff =
      ((unsigned)((jbase >> 5) * 16 + h * 4)) * 1024u + (unsigned)lane * 16u;
#else
  const unsigned short* fp = F + ((size_t)((jbase >> 5) * NH + h) * 4) * 512 + lane * 8;
#endif
  const float* sB = &sEd[h * 1024];

  __syncthreads();   // sEd ready

#pragma unroll
  for (int jt = 0; jt < NJT; ++jt) {
    // SoA exp loads from LDS (shared by all 4 row-groups, compile-time offsets)
    const int off = jt * 32 + q * 8;
    const f32x4 eA[2] = { *(const f32x4*)(sB + off), *(const f32x4*)(sB + off + 4) };
    const f32x4 eB[2] = { *(const f32x4*)(sB + 512 + off),
                          *(const f32x4*)(sB + 512 + off + 4) };

    b16x8 E[4];
#pragma unroll
    for (int rg = 0; rg < 4; ++rg) {
      const unsigned Mb = (m4[rg][jt >> 2] >> ((jt & 3) * 8)) & 0xffu;
      u32x4 pk;
#pragma unroll
      for (int hf = 0; hf < 2; ++hf) {
        const f32x4 xa = eA[hf] * ab[rg].x;   // v_pk_mul_f32 pairs
        const f32x4 xb = eB[hf] * ab[rg].y;
        float e[4];
#pragma unroll
        for (int t2 = 0; t2 < 4; ++t2) {
          const unsigned bit = 1u << (hf * 4 + t2);
          e[t2] = (Mb & bit) ? fmaxf(xa[t2], xb[t2]) : 0.f;
        }
        pk[hf * 2]     = cvtpk(e[0], e[1]);
        pk[hf * 2 + 1] = cvtpk(e[2], e[3]);
      }
      E[rg] = __builtin_bit_cast(b16x8, pk);
    }

#pragma unroll
    for (int g = 0; g < 4; ++g) {
#if FBUF
      const f32x4 bv = __builtin_amdgcn_raw_buffer_load_v4f32(
          frsrc, fvoff + (unsigned)jt * 16384u + (unsigned)g * 1024u, 0, 0);
      const b16x8 bF = __builtin_bit_cast(b16x8, bv);
#else
      const b16x8 bF = __builtin_bit_cast(b16x8,
          *(const u16x8*)(fp + (size_t)(jt * NH * 4 + g) * 512));
#endif
#pragma unroll
      for (int rg = 0; rg < 4; ++rg)
        acc[rg][g] = __builtin_amdgcn_mfma_f32_16x16x32_bf16(E[rg], bF, acc[rg][g], 0, 0, 0);
    }
#pragma unroll
    for (int rg = 0; rg < 4; ++rg)
      lacc[rg] = __builtin_amdgcn_mfma_f32_16x16x32_bf16(E[rg], ones, lacc[rg], 0, 0, 0);
  }

#pragma unroll
  for (int rg = 0; rg < 4; ++rg) {
#pragma unroll
    for (int g = 0; g < 4; ++g)
#pragma unroll
      for (int r = 0; r < 4; ++r) {
        const int col = h * CH + g * 16 + n;
        pacc[((size_t)slice * NN + i0 + rg * 16 + q * 4 + r) * C + col] =
            (_Float16)acc[rg][g][r];
      }
    if (n == 0) {
#pragma unroll
      for (int r = 0; r < 4; ++r)
        lpart[((size_t)slice * NN + i0 + rg * 16 + q * 4 + r) * NH + h] = lacc[rg][r];
    }
  }
}

// ---------------- Kernel 3: combine j-slices, divide (vectorized: f16x2 loads)
__global__ __launch_bounds__(256) void k_final(
    const _Float16* __restrict__ pacc, const float* __restrict__ lpart,
    float* __restrict__ out) {
  const int t = threadIdx.x;
  const int row = blockIdx.x * 2 + (t >> 7);
  const int tc = t & 127;
  const int c2 = tc * 2;
  const int h = tc >> 5;
  float l = 0.f, sa0 = 0.f, sa1 = 0.f;
#pragma unroll
  for (int sp = 0; sp < JSPLIT; ++sp) {
    l += lpart[((size_t)sp * NN + row) * NH + h];
    const f16x2 v = *(const f16x2*)(pacc + ((size_t)sp * NN + row) * C + c2);
    sa0 += (float)v[0];
    sa1 += (float)v[1];
  }
  const float rl = 1.0f / l;
  *(float2*)(out + (size_t)row * C + c2) = make_float2(sa0 * rl, sa1 * rl);
}

extern "C" void kernel_launch(void* const* d_in, const int* in_sizes, int n_in,
                              void* d_out, int out_size, void* d_ws, size_t ws_size,
                              hipStream_t stream) {
  const float* nf   = (const float*)d_in[0];
  const int* adj    = (const int*)d_in[1];
  const float* W    = (const float*)d_in[2];
  const float* bias = (const float*)d_in[3];
  const float* av   = (const float*)d_in[4];
  float* out = (float*)d_out;

  char* ws = (char*)d_ws;
  unsigned char* packed  = (unsigned char*)ws;                              // 2 MB
  unsigned short* Xbf    = (unsigned short*)(ws + (2u << 20));              // 2 MB
  unsigned short* WT     = (unsigned short*)(ws + (4u << 20));              // 128 KB
  unsigned short* F      = (unsigned short*)(ws + (4u << 20) + (256u << 10)); // 2 MB
  float2* srcAB = (float2*)(ws + (6u << 20) + (256u << 10));                // 128 KB
  float* Ed     = (float*)(ws + (6u << 20) + (384u << 10));                 // 128 KB (2 planes)
  float* lpart  = (float*)(ws + (6u << 20) + (512u << 10));                 // 512 KB
  _Float16* pacc = (_Float16*)(ws + (8u << 20));                            // 16 MB

  k_prep<<<1280, 256, 0, stream>>>(nf, W, Xbf, WT);
  k_feats<<<8448, 256, 0, stream>>>(Xbf, WT, bias, av, adj, packed, F, srcAB, Ed);
  dim3 g2(JSPLIT, NN / 64);
  k_attn<<<g2, 256, 0, stream>>>(packed, F, srcAB, Ed, pacc, lpart);
  k_final<<<NN / 2, 256, 0, stream>>>(pacc, lpart, out);
}